// Round 5
// baseline (441.633 us; speedup 1.0000x reference)
//
#include <hip/hip_runtime.h>

#define NB 8192
#define COMPS 4096
#define DIM 768

typedef _Float16 half8_t __attribute__((ext_vector_type(8)));
typedef float floatx4 __attribute__((ext_vector_type(4)));
typedef unsigned short ushort4_t __attribute__((ext_vector_type(4)));
typedef unsigned short ushort8_t __attribute__((ext_vector_type(8)));

typedef __attribute__((address_space(1))) const void* gas_ptr;
typedef __attribute__((address_space(3))) void* las_ptr;

__device__ __forceinline__ void gl_lds16(const _Float16* g, _Float16* l) {
  __builtin_amdgcn_global_load_lds((gas_ptr)(const void*)g, (las_ptr)(void*)l, 16, 0, 0);
}

__device__ __forceinline__ unsigned long long pack_min(float v, int col) {
  unsigned u = __float_as_uint(v);
  u = (u & 0x80000000u) ? ~u : (u | 0x80000000u);
  return ((unsigned long long)u << 32) | (unsigned)col;
}

// ---------------- prep: fp32 -> fp16 hi/lo split ----------------
__global__ void k_prep_e(const float* __restrict__ e,
                         _Float16* __restrict__ ehi, _Float16* __restrict__ elo) {
  int id = blockIdx.x * 256 + threadIdx.x;     // float4 index
  float4 v = ((const float4*)e)[id];
  ushort4_t h, l;
  float xs[4] = {v.x, v.y, v.z, v.w};
#pragma unroll
  for (int q = 0; q < 4; ++q) {
    _Float16 hh = (_Float16)xs[q];
    _Float16 ll = (_Float16)(xs[q] - (float)hh);
    h[q] = __builtin_bit_cast(unsigned short, hh);
    l[q] = __builtin_bit_cast(unsigned short, ll);
  }
  ((ushort4_t*)ehi)[id] = h;
  ((ushort4_t*)elo)[id] = l;
}

// contents: hi/lo split + fp32 row norms. 192 threads, 1 block per row.
__global__ void k_prep_c(const float* __restrict__ c,
                         _Float16* __restrict__ chi, _Float16* __restrict__ clo,
                         float* __restrict__ cnorm) {
  int i = blockIdx.x, t = threadIdx.x;         // 192 threads, 768 = 192*4
  float4 v = ((const float4*)c)[i * 192 + t];
  float xs[4] = {v.x, v.y, v.z, v.w};
  ushort4_t h, l;
  float s = 0.f;
#pragma unroll
  for (int q = 0; q < 4; ++q) {
    _Float16 hh = (_Float16)xs[q];
    _Float16 ll = (_Float16)(xs[q] - (float)hh);
    h[q] = __builtin_bit_cast(unsigned short, hh);
    l[q] = __builtin_bit_cast(unsigned short, ll);
    s = fmaf(xs[q], xs[q], s);
  }
  ((ushort4_t*)chi)[i * 192 + t] = h;
  ((ushort4_t*)clo)[i * 192 + t] = l;
#pragma unroll
  for (int o = 32; o; o >>= 1) s += __shfl_down(s, o);
  __shared__ float red[3];
  if ((t & 63) == 0) red[t >> 6] = s;
  __syncthreads();
  if (t == 0) cnorm[i] = red[0] + red[1] + red[2];
}

// ---------------- E matrix: E[p][q] = exp(-(p-q)^2/(2 sigma^2)), row sums ----
__global__ void k_exps(const float* __restrict__ sigma,
                       float* __restrict__ E, float* __restrict__ rE) {
  int i = blockIdx.x, j = threadIdx.x;         // 64 x 64
  float sg = sigma[0];
  float inv = -1.0f / (2.0f * sg * sg);
  float d = (float)(i - j);
  float v = expf(d * d * inv);
  E[i * 64 + j] = v;
  float s = v;
#pragma unroll
  for (int o = 32; o; o >>= 1) s += __shfl_down(s, o);
  if (j == 0) rE[i] = s;
}

// ---------------- GEMM1: dist + fused argmin (BK=64, XOR swizzle) ----------
__launch_bounds__(256)
__global__ void k_gemm1(const _Float16* __restrict__ ehi, const _Float16* __restrict__ elo,
                        const _Float16* __restrict__ chi, const _Float16* __restrict__ clo,
                        const float* __restrict__ cnorm,
                        unsigned long long* __restrict__ packed) {
  __shared__ _Float16 Ah[128 * 64], Al[128 * 64], Bh[128 * 64], Bl[128 * 64]; // 64 KB
  int tid = threadIdx.x;
  int lane = tid & 63, w = tid >> 6;
  int wr = w >> 1, wc = w & 1;
  int g = lane >> 4, rl = lane & 15;
  int i0 = blockIdx.x * 128, j0 = blockIdx.y * 128;

  // staging: wave w stages its whole 16KB buffer with 16 gl_lds16.
  // LDS rows are 128B (=32 banks), chunk p = c ^ (r&7). Linear LDS dest,
  // inverse-swizzled global source (rule #21).
  int lr = lane >> 3, lc = lane & 7;
  int cch = lc ^ lr;                           // logical chunk for this lane
  const _Float16* gsrc;
  _Float16* dbuf;
  if (w == 0)      { gsrc = ehi + (size_t)i0 * DIM; dbuf = Ah; }
  else if (w == 1) { gsrc = elo + (size_t)i0 * DIM; dbuf = Al; }
  else if (w == 2) { gsrc = chi + (size_t)j0 * DIM; dbuf = Bh; }
  else             { gsrc = clo + (size_t)j0 * DIM; dbuf = Bl; }
  gsrc += (size_t)lr * DIM + cch * 8;
  _Float16* dst = dbuf + lane * 8;             // linear LDS dest (lane*16B)

  floatx4 acc[4][4] = {};

  for (int kt = 0; kt < DIM; kt += 64) {
    __syncthreads();
#pragma unroll
    for (int q = 0; q < 16; ++q)
      gl_lds16(gsrc + kt + (size_t)(q * 8) * DIM, dst + q * 512);
    __syncthreads();

#pragma unroll
    for (int s = 0; s < 2; ++s) {
      half8_t ah[4], al[4];
#pragma unroll
      for (int m = 0; m < 4; ++m) {
        int r = wr * 64 + m * 16 + rl;
        int p = (s * 4 + g) ^ (rl & 7);
        ah[m] = *(half8_t*)&Ah[r * 64 + p * 8];
        al[m] = *(half8_t*)&Al[r * 64 + p * 8];
      }
#pragma unroll
      for (int n = 0; n < 4; ++n) {
        int r = wc * 64 + n * 16 + rl;
        int p = (s * 4 + g) ^ (rl & 7);
        half8_t bh = *(half8_t*)&Bh[r * 64 + p * 8];
        half8_t bl = *(half8_t*)&Bl[r * 64 + p * 8];
#pragma unroll
        for (int m = 0; m < 4; ++m) {
          acc[m][n] = __builtin_amdgcn_mfma_f32_16x16x32_f16(ah[m], bh, acc[m][n], 0, 0, 0);
          acc[m][n] = __builtin_amdgcn_mfma_f32_16x16x32_f16(ah[m], bl, acc[m][n], 0, 0, 0);
          acc[m][n] = __builtin_amdgcn_mfma_f32_16x16x32_f16(al[m], bh, acc[m][n], 0, 0, 0);
        }
      }
    }
  }

  // epilogue: per-row argmin over this block's 128 cols, merge via atomicMin
  float cn[4];
#pragma unroll
  for (int n = 0; n < 4; ++n) cn[n] = cnorm[j0 + wc * 64 + n * 16 + rl];

#pragma unroll
  for (int m = 0; m < 4; ++m) {
#pragma unroll
    for (int j = 0; j < 4; ++j) {
      int row = i0 + wr * 64 + m * 16 + g * 4 + j;
      float best = 3.0e38f;
      int bcol = 0;
#pragma unroll
      for (int n = 0; n < 4; ++n) {
        float d = fmaf(-2.0f, acc[m][n][j], cn[n]);
        int col = j0 + wc * 64 + n * 16 + rl;
        if (d < best) { best = d; bcol = col; }
      }
      unsigned long long pk = pack_min(best, bcol);
#pragma unroll
      for (int o = 1; o < 16; o <<= 1) {
        unsigned long long other = __shfl_xor(pk, o);
        if (other < pk) pk = other;
      }
      if (rl == 0) atomicMin(&packed[row], pk);
    }
  }
}

// ---------------- BMU histogram ----------------
__global__ void k_count(const unsigned long long* __restrict__ packed,
                        int* __restrict__ cnt) {
  int i = blockIdx.x * 256 + threadIdx.x;
  int idx = (int)(packed[i] & 0xffffffffULL);
  atomicAdd(&cnt[idx], 1);
}

// ---------------- exclusive scan of cnt[4096] -> offs, cursor ----------------
__global__ void k_scan(const int* __restrict__ cnt,
                       int* __restrict__ offs, int* __restrict__ cursor) {
  int t = threadIdx.x;                         // 256 threads x 16 elements
  int v[16];
  int tot = 0;
#pragma unroll
  for (int q = 0; q < 16; ++q) { v[q] = cnt[t * 16 + q]; tot += v[q]; }
  int lane = t & 63, wid = t >> 6;
  int s = tot;
#pragma unroll
  for (int o = 1; o < 64; o <<= 1) {
    int u = __shfl_up(s, o);
    if (lane >= o) s += u;
  }
  __shared__ int wt[4];
  if (lane == 63) wt[wid] = s;
  __syncthreads();
  int add = 0;
  for (int w2 = 0; w2 < wid; ++w2) add += wt[w2];
  int run = add + s - tot;                     // exclusive prefix for this thread
#pragma unroll
  for (int q = 0; q < 16; ++q) {
    offs[t * 16 + q] = run;
    cursor[t * 16 + q] = run;
    run += v[q];
  }
}

// ---------------- fill row lists ----------------
__global__ void k_fill(const unsigned long long* __restrict__ packed,
                       int* __restrict__ cursor, int* __restrict__ rows) {
  int i = blockIdx.x * 256 + threadIdx.x;
  int idx = (int)(packed[i] & 0xffffffffULL);
  int pos = atomicAdd(&cursor[idx], 1);
  rows[pos] = i;
}

// ---------------- avg[c] = mean of assigned rows (or cont if none) ----------
__global__ void k_avg(const float* __restrict__ e, const float* __restrict__ cont,
                      const int* __restrict__ cnt, const int* __restrict__ offs,
                      const int* __restrict__ rows, float* __restrict__ avg) {
  int c = blockIdx.x, t = threadIdx.x;         // 192 threads x float4
  int n = cnt[c];
  floatx4 a = {0.f, 0.f, 0.f, 0.f};
  if (n == 0) {
    a = ((const floatx4*)cont)[(size_t)c * 192 + t];
  } else {
    int o0 = offs[c];
    for (int r = 0; r < n; ++r) {
      int i = rows[o0 + r];
      a += ((const floatx4*)e)[(size_t)i * 192 + t];
    }
    a *= (1.0f / (float)n);
  }
  ((floatx4*)avg)[(size_t)c * 192 + t] = a;
}

// ---------------- T1[a][b][d] = sum_b' E[b,b'] * avg[(a,b')][d] ------------
__global__ void k_t1(const float* __restrict__ avg, const float* __restrict__ E,
                     float* __restrict__ T1) {
  __shared__ float S[64 * 128];   // 32 KB: avg slab [b'][d]
  __shared__ float Esh[64 * 64];  // 16 KB
  int a = blockIdx.x, db = blockIdx.y, t = threadIdx.x;
#pragma unroll
  for (int it = 0; it < 8; ++it) {
    int id = t + 256 * it;                     // float4 id 0..2047
    int row = id >> 5, c4 = id & 31;
    ((floatx4*)S)[id] =
        ((const floatx4*)avg)[(size_t)(a * 64 + row) * 192 + db * 32 + c4];
  }
#pragma unroll
  for (int it = 0; it < 4; ++it) {
    int id = t + 256 * it;
    ((floatx4*)Esh)[id] = ((const floatx4*)E)[id];
  }
  __syncthreads();

  int d4 = t & 31, b0 = (t >> 5) * 8;
  floatx4 acc[8] = {};
  for (int bp = 0; bp < 64; ++bp) {
    floatx4 sv = ((floatx4*)S)[bp * 32 + d4];
#pragma unroll
    for (int b = 0; b < 8; ++b)
      acc[b] += Esh[(b0 + b) * 64 + bp] * sv;
  }
#pragma unroll
  for (int b = 0; b < 8; ++b)
    ((floatx4*)T1)[(size_t)(a * 64 + b0 + b) * 192 + db * 32 + d4] = acc[b];
}

// ------ num = sum_a' E[a,a'] T1[a'][b][d]; fused update + rowsq partials ----
__global__ void k_wnum(const float* __restrict__ T1, const float* __restrict__ E,
                       const float* __restrict__ rE, const int* __restrict__ cnt,
                       const float* __restrict__ cont, float* __restrict__ out,
                       float* __restrict__ rowsq) {
  __shared__ float S[64 * 128];   // T1 slab [a'][d]
  __shared__ float Esh[64 * 64];
  int b = blockIdx.x, db = blockIdx.y, t = threadIdx.x;
#pragma unroll
  for (int it = 0; it < 8; ++it) {
    int id = t + 256 * it;
    int ap = id >> 5, c4 = id & 31;
    ((floatx4*)S)[id] = ((const floatx4*)T1)[(size_t)(ap * 64 + b) * 192 + db * 32 + c4];
  }
#pragma unroll
  for (int it = 0; it < 4; ++it) {
    int id = t + 256 * it;
    ((floatx4*)Esh)[id] = ((const floatx4*)E)[id];
  }
  __syncthreads();

  int d4 = t & 31, a0 = (t >> 5) * 8;
  floatx4 acc[8] = {};
  for (int ap = 0; ap < 64; ++ap) {
    floatx4 tv = ((floatx4*)S)[ap * 32 + d4];
#pragma unroll
    for (int a = 0; a < 8; ++a)
      acc[a] += Esh[(a0 + a) * 64 + ap] * tv;
  }

  float rb = rE[b];
  float sq[8];
#pragma unroll
  for (int a = 0; a < 8; ++a) {
    int comp = (a0 + a) * 64 + b;
    bool used = cnt[comp] > 0;
    floatx4 cv = ((const floatx4*)cont)[(size_t)comp * 192 + db * 32 + d4];
    floatx4 val;
    if (used) {
      float inv = 1.0f / (rE[a0 + a] * rb);
      val = acc[a] * inv;
    } else val = cv;
    size_t base = 1 + (size_t)comp * DIM + db * 128 + d4 * 4;
    out[base] = val[0]; out[base + 1] = val[1];
    out[base + 2] = val[2]; out[base + 3] = val[3];
    floatx4 df = val - cv;
    sq[a] = df[0] * df[0] + df[1] * df[1] + df[2] * df[2] + df[3] * df[3];
  }
  // reduce each sq[a] across the 32 lanes sharing this (a-group, db)
#pragma unroll
  for (int a = 0; a < 8; ++a) {
#pragma unroll
    for (int o = 1; o < 32; o <<= 1) sq[a] += __shfl_xor(sq[a], o);
  }
  if (d4 == 0) {
#pragma unroll
    for (int a = 0; a < 8; ++a)
      unsafeAtomicAdd(&rowsq[(a0 + a) * 64 + b], sq[a]);
  }
}

// ---------------- delta = sum_c sqrt(rowsq[c]) ----------------
__global__ void k_deltaf(const float* __restrict__ rowsq, float* __restrict__ out) {
  int t = threadIdx.x;
  double s = 0.0;
  for (int c = t; c < COMPS; c += 256) s += sqrt((double)rowsq[c]);
#pragma unroll
  for (int o = 32; o; o >>= 1) s += __shfl_down(s, o);
  __shared__ double red[4];
  if ((t & 63) == 0) red[t >> 6] = s;
  __syncthreads();
  if (t == 0) out[0] = (float)(red[0] + red[1] + red[2] + red[3]);
}

extern "C" void kernel_launch(void* const* d_in, const int* in_sizes, int n_in,
                              void* d_out, int out_size, void* d_ws, size_t ws_size,
                              hipStream_t stream) {
  const float* e = (const float*)d_in[0];       // [8192, 768]
  const float* cont = (const float*)d_in[1];    // [64, 64, 768]
  // d_in[2] (grid_dists) not read: W = E (x) E separable
  const float* sigma = (const float*)d_in[3];   // [1]
  float* out = (float*)d_out;                   // [1 + 4096*768]

  char* ws = (char*)d_ws;
  size_t off = 0;
  auto take = [&](size_t bytes) { char* p = ws + off; off += (bytes + 255) & ~(size_t)255; return p; };

  unsigned long long* packed = (unsigned long long*)take(NB * 8);
  int* cnt    = (int*)take(COMPS * 4);
  int* offs   = (int*)take(COMPS * 4);
  int* cursor = (int*)take(COMPS * 4);
  int* rows   = (int*)take(NB * 4);
  float* rowsq = (float*)take(COMPS * 4);
  float* cnorm = (float*)take(COMPS * 4);
  float* E     = (float*)take(64 * 64 * 4);
  float* rE    = (float*)take(64 * 4);
  float* avg   = (float*)take((size_t)COMPS * DIM * 4);
  // union region: {ehi, elo, chi, clo} during GEMM1; T1 aliases chi+clo after
  char* U = take((size_t)NB * DIM * 2 * 2 + (size_t)COMPS * DIM * 2 * 2);
  _Float16* ehi = (_Float16*)U;
  _Float16* elo = (_Float16*)(U + (size_t)NB * DIM * 2);
  _Float16* chi = (_Float16*)(U + (size_t)NB * DIM * 4);
  _Float16* clo = (_Float16*)(U + (size_t)NB * DIM * 4 + (size_t)COMPS * DIM * 2);
  float* T1 = (float*)(U + (size_t)NB * DIM * 4);   // 12.58MB = chi+clo region

  hipMemsetAsync(packed, 0xFF, NB * 8, stream);
  hipMemsetAsync(cnt, 0, COMPS * 4, stream);
  hipMemsetAsync(rowsq, 0, COMPS * 4, stream);

  k_prep_e<<<(NB * DIM / 4) / 256, 256, 0, stream>>>(e, ehi, elo);
  k_prep_c<<<COMPS, 192, 0, stream>>>(cont, chi, clo, cnorm);
  k_exps<<<64, 64, 0, stream>>>(sigma, E, rE);
  k_gemm1<<<dim3(NB / 128, COMPS / 128), 256, 0, stream>>>(ehi, elo, chi, clo, cnorm, packed);
  k_count<<<NB / 256, 256, 0, stream>>>(packed, cnt);
  k_scan<<<1, 256, 0, stream>>>(cnt, offs, cursor);
  k_fill<<<NB / 256, 256, 0, stream>>>(packed, cursor, rows);
  k_avg<<<COMPS, 192, 0, stream>>>(e, cont, cnt, offs, rows, avg);
  k_t1<<<dim3(64, 6), 256, 0, stream>>>(avg, E, T1);
  k_wnum<<<dim3(64, 6), 256, 0, stream>>>(T1, E, rE, cnt, cont, out, rowsq);
  k_deltaf<<<1, 256, 0, stream>>>(rowsq, out);
}

// Round 6
// 345.582 us; speedup vs baseline: 1.2779x; 1.2779x over previous
//
#include <hip/hip_runtime.h>

#define NB 8192
#define COMPS 4096
#define DIM 768

typedef _Float16 half8_t __attribute__((ext_vector_type(8)));
typedef float floatx4 __attribute__((ext_vector_type(4)));
typedef unsigned short ushort4_t __attribute__((ext_vector_type(4)));
typedef unsigned short ushort8_t __attribute__((ext_vector_type(8)));
typedef unsigned long long ullx2 __attribute__((ext_vector_type(2)));

typedef __attribute__((address_space(1))) const void* gas_ptr;
typedef __attribute__((address_space(3))) void* las_ptr;

__device__ __forceinline__ void gl_lds16(const _Float16* g, _Float16* l) {
  __builtin_amdgcn_global_load_lds((gas_ptr)(const void*)g, (las_ptr)(void*)l, 16, 0, 0);
}

__device__ __forceinline__ unsigned long long pack_min(float v, int col) {
  unsigned u = __float_as_uint(v);
  u = (u & 0x80000000u) ? ~u : (u | 0x80000000u);
  return ((unsigned long long)u << 32) | (unsigned)col;
}

// ================= fused prep: e-split | c-split+cnorm | E+rE | zeroing =====
// grid ranges:
//   [0,6144)        e hi/lo split (256 thr, float4 each)
//   [6144,10240)    c hi/lo split + cnorm (one comp/block, 192 of 256 thr)
//   [10240,10304)   E + rE (one row/block, 64 of 256 thr)
//   [10304,13376)   zero sums (float4)
//   [13376,13392)   packed = 0xFF (ullx2)
//   [13392,13396)   zero freq (float4)
//   [13396,13400)   zero rowsq (float4)
//   13400           done = 0
#define PREP_GRID 13401
__global__ void k_prep(const float* __restrict__ e, const float* __restrict__ c,
                       const float* __restrict__ sigma,
                       _Float16* __restrict__ ehi, _Float16* __restrict__ elo,
                       _Float16* __restrict__ chi, _Float16* __restrict__ clo,
                       float* __restrict__ cnorm, float* __restrict__ E,
                       float* __restrict__ rE, float* __restrict__ sums,
                       float* __restrict__ freq, float* __restrict__ rowsq,
                       unsigned long long* __restrict__ packed,
                       unsigned int* __restrict__ done) {
  int bx = blockIdx.x, t = threadIdx.x;
  if (bx < 6144) {
    int id = bx * 256 + t;
    float4 v = ((const float4*)e)[id];
    ushort4_t h, l;
    float xs[4] = {v.x, v.y, v.z, v.w};
#pragma unroll
    for (int q = 0; q < 4; ++q) {
      _Float16 hh = (_Float16)xs[q];
      _Float16 ll = (_Float16)(xs[q] - (float)hh);
      h[q] = __builtin_bit_cast(unsigned short, hh);
      l[q] = __builtin_bit_cast(unsigned short, ll);
    }
    ((ushort4_t*)ehi)[id] = h;
    ((ushort4_t*)elo)[id] = l;
  } else if (bx < 10240) {
    int i = bx - 6144;
    float s = 0.f;
    if (t < 192) {
      float4 v = ((const float4*)c)[i * 192 + t];
      float xs[4] = {v.x, v.y, v.z, v.w};
      ushort4_t h, l;
#pragma unroll
      for (int q = 0; q < 4; ++q) {
        _Float16 hh = (_Float16)xs[q];
        _Float16 ll = (_Float16)(xs[q] - (float)hh);
        h[q] = __builtin_bit_cast(unsigned short, hh);
        l[q] = __builtin_bit_cast(unsigned short, ll);
        s = fmaf(xs[q], xs[q], s);
      }
      ((ushort4_t*)chi)[i * 192 + t] = h;
      ((ushort4_t*)clo)[i * 192 + t] = l;
    }
#pragma unroll
    for (int o = 32; o; o >>= 1) s += __shfl_down(s, o);
    __shared__ float red[3];
    if (t < 192 && (t & 63) == 0) red[t >> 6] = s;
    __syncthreads();
    if (t == 0) cnorm[i] = red[0] + red[1] + red[2];
  } else if (bx < 10304) {
    int i = bx - 10240;
    if (t < 64) {
      float sg = sigma[0];
      float inv = -1.0f / (2.0f * sg * sg);
      float d = (float)(i - t);
      float v = expf(d * d * inv);
      E[i * 64 + t] = v;
      float s = v;
#pragma unroll
      for (int o = 32; o; o >>= 1) s += __shfl_down(s, o);
      if (t == 0) rE[i] = s;
    }
  } else if (bx < 13376) {
    int id = (bx - 10304) * 256 + t;
    floatx4 z = {0.f, 0.f, 0.f, 0.f};
    ((floatx4*)sums)[id] = z;
  } else if (bx < 13392) {
    int id = (bx - 13376) * 256 + t;
    ullx2 f = {~0ULL, ~0ULL};
    ((ullx2*)packed)[id] = f;
  } else if (bx < 13396) {
    int id = (bx - 13392) * 256 + t;
    floatx4 z = {0.f, 0.f, 0.f, 0.f};
    ((floatx4*)freq)[id] = z;
  } else if (bx < 13400) {
    int id = (bx - 13396) * 256 + t;
    floatx4 z = {0.f, 0.f, 0.f, 0.f};
    ((floatx4*)rowsq)[id] = z;
  } else {
    if (t == 0) *done = 0u;
  }
}

// ---------------- GEMM1: dist + fused argmin (BK=64, XOR swizzle) ----------
__launch_bounds__(256)
__global__ void k_gemm1(const _Float16* __restrict__ ehi, const _Float16* __restrict__ elo,
                        const _Float16* __restrict__ chi, const _Float16* __restrict__ clo,
                        const float* __restrict__ cnorm,
                        unsigned long long* __restrict__ packed) {
  __shared__ _Float16 Ah[128 * 64], Al[128 * 64], Bh[128 * 64], Bl[128 * 64]; // 64 KB
  int tid = threadIdx.x;
  int lane = tid & 63, w = tid >> 6;
  int wr = w >> 1, wc = w & 1;
  int g = lane >> 4, rl = lane & 15;
  int i0 = blockIdx.x * 128, j0 = blockIdx.y * 128;

  // staging: wave w stages its whole 16KB buffer with 16 gl_lds16.
  // LDS rows are 128B (=32 banks), chunk p = c ^ (r&7). Linear LDS dest,
  // inverse-swizzled global source (rule #21).
  int lr = lane >> 3, lc = lane & 7;
  int cch = lc ^ lr;                           // logical chunk for this lane
  const _Float16* gsrc;
  _Float16* dbuf;
  if (w == 0)      { gsrc = ehi + (size_t)i0 * DIM; dbuf = Ah; }
  else if (w == 1) { gsrc = elo + (size_t)i0 * DIM; dbuf = Al; }
  else if (w == 2) { gsrc = chi + (size_t)j0 * DIM; dbuf = Bh; }
  else             { gsrc = clo + (size_t)j0 * DIM; dbuf = Bl; }
  gsrc += (size_t)lr * DIM + cch * 8;
  _Float16* dst = dbuf + lane * 8;             // linear LDS dest (lane*16B)

  floatx4 acc[4][4] = {};

  for (int kt = 0; kt < DIM; kt += 64) {
    __syncthreads();
#pragma unroll
    for (int q = 0; q < 16; ++q)
      gl_lds16(gsrc + kt + (size_t)(q * 8) * DIM, dst + q * 512);
    __syncthreads();

#pragma unroll
    for (int s = 0; s < 2; ++s) {
      half8_t ah[4], al[4];
#pragma unroll
      for (int m = 0; m < 4; ++m) {
        int r = wr * 64 + m * 16 + rl;
        int p = (s * 4 + g) ^ (rl & 7);
        ah[m] = *(half8_t*)&Ah[r * 64 + p * 8];
        al[m] = *(half8_t*)&Al[r * 64 + p * 8];
      }
#pragma unroll
      for (int n = 0; n < 4; ++n) {
        int r = wc * 64 + n * 16 + rl;
        int p = (s * 4 + g) ^ (rl & 7);
        half8_t bh = *(half8_t*)&Bh[r * 64 + p * 8];
        half8_t bl = *(half8_t*)&Bl[r * 64 + p * 8];
#pragma unroll
        for (int m = 0; m < 4; ++m) {
          acc[m][n] = __builtin_amdgcn_mfma_f32_16x16x32_f16(ah[m], bh, acc[m][n], 0, 0, 0);
          acc[m][n] = __builtin_amdgcn_mfma_f32_16x16x32_f16(ah[m], bl, acc[m][n], 0, 0, 0);
          acc[m][n] = __builtin_amdgcn_mfma_f32_16x16x32_f16(al[m], bh, acc[m][n], 0, 0, 0);
        }
      }
    }
  }

  // epilogue: per-row argmin over this block's 128 cols, merge via atomicMin
  float cn[4];
#pragma unroll
  for (int n = 0; n < 4; ++n) cn[n] = cnorm[j0 + wc * 64 + n * 16 + rl];

#pragma unroll
  for (int m = 0; m < 4; ++m) {
#pragma unroll
    for (int j = 0; j < 4; ++j) {
      int row = i0 + wr * 64 + m * 16 + g * 4 + j;
      float best = 3.0e38f;
      int bcol = 0;
#pragma unroll
      for (int n = 0; n < 4; ++n) {
        float d = fmaf(-2.0f, acc[m][n][j], cn[n]);
        int col = j0 + wc * 64 + n * 16 + rl;
        if (d < best) { best = d; bcol = col; }
      }
      unsigned long long pk = pack_min(best, bcol);
#pragma unroll
      for (int o = 1; o < 16; o <<= 1) {
        unsigned long long other = __shfl_xor(pk, o);
        if (other < pk) pk = other;
      }
      if (rl == 0) atomicMin(&packed[row], pk);
    }
  }
}

// ---------------- scatter: freq + per-comp sums ----------------
__global__ void k_scatter(const float* __restrict__ e,
                          const unsigned long long* __restrict__ packed,
                          float* __restrict__ freq, float* __restrict__ sums) {
  int i = blockIdx.x, t = threadIdx.x;
  int idx = (int)(packed[i] & 0xffffffffULL);
  if (t == 0) unsafeAtomicAdd(&freq[idx], 1.0f);
#pragma unroll
  for (int r = 0; r < 3; ++r) {
    int d = t + 256 * r;
    unsafeAtomicAdd(&sums[(size_t)idx * DIM + d], e[(size_t)i * DIM + d]);
  }
}

// ---------------- T1[a][b][d] = sum_b' E[b,b'] * avg[(a,b')][d] ------------
// grid (64 a, 6 dblk), block 256. avg computed on the fly from sums/freq/cont.
__global__ void k_t1(const float* __restrict__ sums, const float* __restrict__ freq,
                     const float* __restrict__ cont, const float* __restrict__ E,
                     float* __restrict__ T1) {
  __shared__ float S[64 * 128];   // 32 KB: avg slab [b'][d]
  __shared__ float Esh[64 * 64];  // 16 KB
  int a = blockIdx.x, db = blockIdx.y, t = threadIdx.x;
#pragma unroll
  for (int it = 0; it < 8; ++it) {
    int id = t + 256 * it;                     // float4 id 0..2047
    int row = id >> 5, c4 = id & 31;
    int comp = a * 64 + row;
    float f = freq[comp];
    size_t o = (size_t)comp * 192 + db * 32 + c4;
    floatx4 v;
    if (f > 0.f) {
      floatx4 sv = ((const floatx4*)sums)[o];
      float inv = 1.0f / f;
      v = sv * inv;
    } else v = ((const floatx4*)cont)[o];
    ((floatx4*)S)[id] = v;
  }
#pragma unroll
  for (int it = 0; it < 4; ++it) {
    int id = t + 256 * it;
    ((floatx4*)Esh)[id] = ((const floatx4*)E)[id];
  }
  __syncthreads();

  int d4 = t & 31, b0 = (t >> 5) * 8;
  floatx4 acc[8] = {};
  for (int bp = 0; bp < 64; ++bp) {
    floatx4 sv = ((floatx4*)S)[bp * 32 + d4];
#pragma unroll
    for (int b = 0; b < 8; ++b)
      acc[b] += Esh[(b0 + b) * 64 + bp] * sv;
  }
#pragma unroll
  for (int b = 0; b < 8; ++b)
    ((floatx4*)T1)[(size_t)(a * 64 + b0 + b) * 192 + db * 32 + d4] = acc[b];
}

// ------ num = sum_a' E[a,a'] T1[a'][b][d]; update + rowsq + fused delta ----
__global__ void k_wnum(const float* __restrict__ T1, const float* __restrict__ E,
                       const float* __restrict__ rE, const float* __restrict__ freq,
                       const float* __restrict__ cont, float* __restrict__ out,
                       float* __restrict__ rowsq, unsigned int* __restrict__ done) {
  __shared__ float S[64 * 128];   // T1 slab [a'][d]
  __shared__ float Esh[64 * 64];
  int b = blockIdx.x, db = blockIdx.y, t = threadIdx.x;
#pragma unroll
  for (int it = 0; it < 8; ++it) {
    int id = t + 256 * it;
    int ap = id >> 5, c4 = id & 31;
    ((floatx4*)S)[id] = ((const floatx4*)T1)[(size_t)(ap * 64 + b) * 192 + db * 32 + c4];
  }
#pragma unroll
  for (int it = 0; it < 4; ++it) {
    int id = t + 256 * it;
    ((floatx4*)Esh)[id] = ((const floatx4*)E)[id];
  }
  __syncthreads();

  int d4 = t & 31, a0 = (t >> 5) * 8;
  floatx4 acc[8] = {};
  for (int ap = 0; ap < 64; ++ap) {
    floatx4 tv = ((floatx4*)S)[ap * 32 + d4];
#pragma unroll
    for (int a = 0; a < 8; ++a)
      acc[a] += Esh[(a0 + a) * 64 + ap] * tv;
  }

  float rb = rE[b];
  float sq[8];
#pragma unroll
  for (int a = 0; a < 8; ++a) {
    int comp = (a0 + a) * 64 + b;
    bool used = freq[comp] > 0.f;
    floatx4 cv = ((const floatx4*)cont)[(size_t)comp * 192 + db * 32 + d4];
    floatx4 val;
    if (used) {
      float inv = 1.0f / (rE[a0 + a] * rb);
      val = acc[a] * inv;
    } else val = cv;
    size_t base = 1 + (size_t)comp * DIM + db * 128 + d4 * 4;
    out[base] = val[0]; out[base + 1] = val[1];
    out[base + 2] = val[2]; out[base + 3] = val[3];
    floatx4 df = val - cv;
    sq[a] = df[0] * df[0] + df[1] * df[1] + df[2] * df[2] + df[3] * df[3];
  }
#pragma unroll
  for (int a = 0; a < 8; ++a) {
#pragma unroll
    for (int o = 1; o < 32; o <<= 1) sq[a] += __shfl_xor(sq[a], o);
  }
  if (d4 == 0) {
#pragma unroll
    for (int a = 0; a < 8; ++a)
      unsafeAtomicAdd(&rowsq[(a0 + a) * 64 + b], sq[a]);
  }

  // ---- fused delta: last of the 384 blocks reduces rowsq ----
  // __syncthreads() drains vmcnt (compiler emits s_waitcnt vmcnt(0) before
  // s_barrier), so this block's rowsq atomics are globally visible before
  // the ticket increment.
  __shared__ unsigned int lastflag;
  __syncthreads();
  if (t == 0) {
    __threadfence();
    unsigned int old = atomicAdd(done, 1u);
    lastflag = (old == 64u * 6u - 1u) ? 1u : 0u;
  }
  __syncthreads();
  if (lastflag) {
    double s = 0.0;
    for (int c2 = t; c2 < COMPS; c2 += 256) {
      float r = __hip_atomic_load(&rowsq[c2], __ATOMIC_RELAXED,
                                  __HIP_MEMORY_SCOPE_AGENT);
      s += sqrt((double)r);
    }
#pragma unroll
    for (int o = 32; o; o >>= 1) s += __shfl_down(s, o);
    __shared__ double red[4];
    if ((t & 63) == 0) red[t >> 6] = s;
    __syncthreads();
    if (t == 0) out[0] = (float)(red[0] + red[1] + red[2] + red[3]);
  }
}

extern "C" void kernel_launch(void* const* d_in, const int* in_sizes, int n_in,
                              void* d_out, int out_size, void* d_ws, size_t ws_size,
                              hipStream_t stream) {
  const float* e = (const float*)d_in[0];       // [8192, 768]
  const float* cont = (const float*)d_in[1];    // [64, 64, 768]
  // d_in[2] (grid_dists) not read: W = E (x) E separable
  const float* sigma = (const float*)d_in[3];   // [1]
  float* out = (float*)d_out;                   // [1 + 4096*768]

  char* ws = (char*)d_ws;
  size_t off = 0;
  auto take = [&](size_t bytes) { char* p = ws + off; off += (bytes + 255) & ~(size_t)255; return p; };

  unsigned long long* packed = (unsigned long long*)take(NB * 8);
  float* freq  = (float*)take(COMPS * 4);
  float* rowsq = (float*)take(COMPS * 4);
  float* cnorm = (float*)take(COMPS * 4);
  float* E     = (float*)take(64 * 64 * 4);
  float* rE    = (float*)take(64 * 4);
  unsigned int* done = (unsigned int*)take(256);
  float* sums  = (float*)take((size_t)COMPS * DIM * 4);
  // union region: {ehi, elo, chi, clo} during GEMM1; T1 aliases chi+clo after
  char* U = take((size_t)NB * DIM * 2 * 2 + (size_t)COMPS * DIM * 2 * 2);
  _Float16* ehi = (_Float16*)U;
  _Float16* elo = (_Float16*)(U + (size_t)NB * DIM * 2);
  _Float16* chi = (_Float16*)(U + (size_t)NB * DIM * 4);
  _Float16* clo = (_Float16*)(U + (size_t)NB * DIM * 4 + (size_t)COMPS * DIM * 2);
  float* T1 = (float*)(U + (size_t)NB * DIM * 4);   // 12.58MB = chi+clo region

  k_prep<<<PREP_GRID, 256, 0, stream>>>(e, cont, sigma, ehi, elo, chi, clo,
                                        cnorm, E, rE, sums, freq, rowsq,
                                        packed, done);
  k_gemm1<<<dim3(NB / 128, COMPS / 128), 256, 0, stream>>>(ehi, elo, chi, clo, cnorm, packed);
  k_scatter<<<NB, 256, 0, stream>>>(e, packed, freq, sums);
  k_t1<<<dim3(64, 6), 256, 0, stream>>>(sums, freq, cont, E, T1);
  k_wnum<<<dim3(64, 6), 256, 0, stream>>>(T1, E, rE, freq, cont, out, rowsq, done);
}